// Round 9
// baseline (145.355 us; speedup 1.0000x reference)
//
#include <hip/hip_runtime.h>
#include <math.h>

typedef _Float16 h4 __attribute__((ext_vector_type(4)));
typedef _Float16 h2 __attribute__((ext_vector_type(2)));
typedef float    f4 __attribute__((ext_vector_type(4)));

namespace {
constexpr float LB = 4.5f;                       // HSGP half-domain
constexpr float WF = (float)M_PI / (2.0f * LB);  // base frequency
}

// ---------------------------------------------------------------------------
// Setup: build the 3 shared A-fragments for v_mfma_f32_16x16x16_f16.
// A_d[row=a][k=j] = beta[d, a*12+j] * sqrt(S(a,j)) / LB, padded to 16x16.
// Fragment layout: lane l holds A[l&15][4*(l>>4)+t], t=0..3.
// ---------------------------------------------------------------------------
__global__ void setup_A_kernel(const float* __restrict__ beta,
                               const float* __restrict__ ls,
                               const float* __restrict__ alpha,
                               _Float16* __restrict__ A) {
    int idx = blockIdx.x * blockDim.x + threadIdx.x;
    if (idx >= 768) return;
    int d = idx >> 8;
    int l = (idx >> 2) & 63;
    int t = idx & 3;
    int r = l & 15;                 // output row = a index
    int k = ((l >> 4) << 2) + t;    // K index   = j index
    float val = 0.0f;
    if (r < 12 && k < 12) {
        float w0 = WF * (float)(r + 1);
        float w1 = WF * (float)(k + 1);
        float l0 = ls[0], l1 = ls[1], al = alpha[0];
        float S = al * al * (2.0f * (float)M_PI) * l0 * l1 *
                  expf(-0.5f * (l0 * l0 * w0 * w0 + l1 * l1 * w1 * w1));
        val = beta[d * 144 + r * 12 + k] * sqrtf(S) * (1.0f / LB);
    }
    A[idx] = (_Float16)val;
}

// ---------------------------------------------------------------------------
// 4 consecutive multiples mb..mb+3 of angle th via HW sincos + angle-addition.
// ---------------------------------------------------------------------------
__device__ __forceinline__ void trig4(float th, float mb, float* s, float* c) {
    float s1 = __sinf(th), c1 = __cosf(th);
    float sb = __sinf(mb * th), cb = __cosf(mb * th);
    s[0] = sb; c[0] = cb;
    #pragma unroll
    for (int t = 1; t < 4; ++t) {
        s[t] = fmaf(s[t - 1], c1,  c[t - 1] * s1);
        c[t] = fmaf(c[t - 1], c1, -(s[t - 1] * s1));
    }
}

__device__ __forceinline__ h4 pack4(float a, float b, float c, float d) {
    h2 lo = __builtin_bit_cast(h2, __builtin_amdgcn_cvt_pkrtz(a, b));
    h2 hi = __builtin_bit_cast(h2, __builtin_amdgcn_cvt_pkrtz(c, d));
    return __builtin_shufflevector(lo, hi, 0, 1, 2, 3);
}

// ---------------------------------------------------------------------------
// Main: one wave = 16 elements (element = lane&15, lane-group g = lane>>4
// owns a-rows 4g..4g+3). Two MFMA stages per step:
//   stage 1: u_d = M_d * s1, w_d = M_d * wc1      (A = M_d shared, f16)
//   stage 2: A = all-ones: D[row][col] = sum_k P[k][col] with lane-local
//            premultiplied partials P (s0*u, wc0*u, s0*w). Every row of D
//            carries the full a-sum -> every lane-group gets every sum in
//            every reg. NO cross-lane shuffles anywhere in the loop (round
//            6's 10 ds_bpermute chains were ~300 serial cyc/step).
// ---------------------------------------------------------------------------
__global__ __launch_bounds__(64)
void geo_kernel(const float* __restrict__ xg, const float* __restrict__ vg,
                const _Float16* Ag /* non-restrict-ish: pinned below */,
                float* __restrict__ out, int B)
{
    int lane = threadIdx.x;
    int ebase = blockIdx.x << 4;
    if (ebase >= B) return;
    int g = lane >> 4;
    int e = ebase + (lane & 15);
    if (e >= B) e = B - 1;          // benign clamp (duplicate writes identical)

    // ---- shared A fragments (6 VGPRs) + ones fragment ----
    union U8 { uint2 u; h4 h; };
    const uint2* Au = reinterpret_cast<const uint2*>(Ag);
    U8 a0, a1, a2;
    a0.u = Au[0 * 64 + lane];
    a1.u = Au[1 * 64 + lane];
    a2.u = Au[2 * 64 + lane];
    asm volatile("" ::: "memory");  // forbid reload of Ag inside the loop
    h4 A0 = a0.h, A1 = a1.h, A2 = a2.h;
    h4 ONES = {(_Float16)1.0f, (_Float16)1.0f, (_Float16)1.0f, (_Float16)1.0f};

    float mb = (float)(4 * g + 1);
    float Wm[4];
    #pragma unroll
    for (int t = 0; t < 4; ++t) Wm[t] = WF * (mb + (float)t);

    float2 xv = reinterpret_cast<const float2*>(xg)[e];
    float2 vv2 = reinterpret_cast<const float2*>(vg)[e];
    float x0 = xv.x, x1 = xv.y, v0 = vv2.x, v1 = vv2.y;

    // per-lane output slot: out[t][g>>1][e][g&1]
    unsigned off = 4u * ((((unsigned)(g >> 1) * (unsigned)B) + (unsigned)e) * 2u
                         + (unsigned)(g & 1));
    const unsigned stride = 16u * (unsigned)B;   // bytes per time slot
    char* outc = reinterpret_cast<char*>(out);
    {
        float sval = (g & 2) ? ((g & 1) ? v1 : v0) : ((g & 1) ? x1 : x0);
        *reinterpret_cast<float*>(outc + off) = sval;
    }

    // Adams histories (older entries)
    float h1x = 0.f, h2x = 0.f, h3x = 0.f, h1y = 0.f, h2y = 0.f, h3y = 0.f;
    float g1x = 0.f, g2x = 0.f, g3x = 0.f, g1y = 0.f, g2y = 0.f, g3y = 0.f;
    const float h = 1.0f / 99.0f;

    auto STEP = [&](float c0, float c1c, float c2c, float c3c) {
        // ---- per-lane trig: multiples 4g+1..4g+4 of both dims ----
        float s0v[4], c0v[4], s1v[4], c1v[4], wc0[4];
        trig4(WF * (x0 + LB), mb, s0v, c0v);
        trig4(WF * (x1 + LB), mb, s1v, c1v);
        #pragma unroll
        for (int t = 0; t < 4; ++t) wc0[t] = Wm[t] * c0v[t];

        h4 bs = pack4(s1v[0], s1v[1], s1v[2], s1v[3]);
        h4 bc = pack4(Wm[0] * c1v[0], Wm[1] * c1v[1],
                      Wm[2] * c1v[2], Wm[3] * c1v[3]);

        // ---- stage 1: u_d = M_d*s1, w_d = M_d*wc1 ----
        f4 z = {0.f, 0.f, 0.f, 0.f};
        f4 u0 = __builtin_amdgcn_mfma_f32_16x16x16f16(A0, bs, z, 0, 0, 0);
        f4 u1 = __builtin_amdgcn_mfma_f32_16x16x16f16(A1, bs, z, 0, 0, 0);
        f4 u2 = __builtin_amdgcn_mfma_f32_16x16x16f16(A2, bs, z, 0, 0, 0);
        f4 w0 = __builtin_amdgcn_mfma_f32_16x16x16f16(A0, bc, z, 0, 0, 0);
        f4 w1 = __builtin_amdgcn_mfma_f32_16x16x16f16(A1, bc, z, 0, 0, 0);
        f4 w2 = __builtin_amdgcn_mfma_f32_16x16x16f16(A2, bc, z, 0, 0, 0);

        // ---- lane-local premultiplied partials (rows 12..15 are exactly 0) --
        h4 Pf0 = pack4(s0v[0]*u0[0], s0v[1]*u0[1], s0v[2]*u0[2], s0v[3]*u0[3]);
        h4 Pf1 = pack4(s0v[0]*u1[0], s0v[1]*u1[1], s0v[2]*u1[2], s0v[3]*u1[3]);
        h4 Pf2 = pack4(s0v[0]*u2[0], s0v[1]*u2[1], s0v[2]*u2[2], s0v[3]*u2[3]);
        h4 Pa0 = pack4(wc0[0]*u0[0], wc0[1]*u0[1], wc0[2]*u0[2], wc0[3]*u0[3]);
        h4 Pa1 = pack4(wc0[0]*u1[0], wc0[1]*u1[1], wc0[2]*u1[2], wc0[3]*u1[3]);
        h4 Pa2 = pack4(wc0[0]*u2[0], wc0[1]*u2[1], wc0[2]*u2[2], wc0[3]*u2[3]);
        h4 Pb0 = pack4(s0v[0]*w0[0], s0v[1]*w0[1], s0v[2]*w0[2], s0v[3]*w0[3]);
        h4 Pb1 = pack4(s0v[0]*w1[0], s0v[1]*w1[1], s0v[2]*w1[2], s0v[3]*w1[3]);
        h4 Pb2 = pack4(s0v[0]*w2[0], s0v[1]*w2[1], s0v[2]*w2[2], s0v[3]*w2[3]);

        // ---- stage 2: ones-A row-sums -> every lane gets the full a-sum ----
        f4 F0  = __builtin_amdgcn_mfma_f32_16x16x16f16(ONES, Pf0, z, 0, 0, 0);
        f4 F1  = __builtin_amdgcn_mfma_f32_16x16x16f16(ONES, Pf1, z, 0, 0, 0);
        f4 F2  = __builtin_amdgcn_mfma_f32_16x16x16f16(ONES, Pf2, z, 0, 0, 0);
        f4 DA0 = __builtin_amdgcn_mfma_f32_16x16x16f16(ONES, Pa0, z, 0, 0, 0);
        f4 DA1 = __builtin_amdgcn_mfma_f32_16x16x16f16(ONES, Pa1, z, 0, 0, 0);
        f4 DA2 = __builtin_amdgcn_mfma_f32_16x16x16f16(ONES, Pa2, z, 0, 0, 0);
        f4 DB0 = __builtin_amdgcn_mfma_f32_16x16x16f16(ONES, Pb0, z, 0, 0, 0);
        f4 DB1 = __builtin_amdgcn_mfma_f32_16x16x16f16(ONES, Pb1, z, 0, 0, 0);
        f4 DB2 = __builtin_amdgcn_mfma_f32_16x16x16f16(ONES, Pb2, z, 0, 0, 0);

        float f0 = F0[0], f1 = F1[0], f2 = F2[0];
        float dA0 = DA0[0], dA1 = DA1[0], dA2 = DA2[0];
        float dB0 = DB0[0], dB1 = DB1[0], dB2 = DB2[0];

        // ---- Christoffel acceleration (identical on all lanes of element) --
        float vv00 = v0 * v0, vv01 = v0 * v1, vv11 = v1 * v1;
        float q0p = dA0 * vv00 + 2.0f * dB0 * vv01 + fmaf(2.0f, dB1, -dA2) * vv11;
        float q1p = fmaf(2.0f, dA1, -dB0) * vv00 + 2.0f * dA2 * vv01 + dB2 * vv11;

        float G00 = f0 + 1.0f, G01 = f1, G11 = f2 + 1.0f;
        float det = fmaf(G00, G11, -(G01 * G01));
        float rdet = __builtin_amdgcn_rcpf(det);
        float a0v = -0.5f * rdet * fmaf(G11, q0p, -(G01 * q1p));
        float a1v = -0.5f * rdet * fmaf(G00, q1p, -(G01 * q0p));

        // ---- Adams-Bashforth update ----
        float dx0 = fmaf(c0, v0, fmaf(c1c, h1x, fmaf(c2c, h2x, c3c * h3x)));
        float dx1 = fmaf(c0, v1, fmaf(c1c, h1y, fmaf(c2c, h2y, c3c * h3y)));
        float dv0 = fmaf(c0, a0v, fmaf(c1c, g1x, fmaf(c2c, g2x, c3c * g3x)));
        float dv1 = fmaf(c0, a1v, fmaf(c1c, g1y, fmaf(c2c, g2y, c3c * g3y)));
        h3x = h2x; h2x = h1x; h1x = v0;  h3y = h2y; h2y = h1y; h1y = v1;
        g3x = g2x; g2x = g1x; g1x = a0v; g3y = g2y; g2y = g1y; g1y = a1v;
        x0 = fmaf(h, dx0, x0); x1 = fmaf(h, dx1, x1);
        v0 = fmaf(h, dv0, v0); v1 = fmaf(h, dv1, v1);

        off += stride;
        float sval = (g & 2) ? ((g & 1) ? v1 : v0) : ((g & 1) ? x1 : x0);
        *reinterpret_cast<float*>(outc + off) = sval;
    };

    // startup (orders 1..3), then steady AB4 (96 = 24*4 iterations)
    STEP(1.0f, 0.0f, 0.0f, 0.0f);
    STEP(1.5f, -0.5f, 0.0f, 0.0f);
    STEP(23.0f / 12.0f, -16.0f / 12.0f, 5.0f / 12.0f, 0.0f);
    #pragma unroll 4
    for (int t = 3; t < 99; ++t)
        STEP(55.0f / 24.0f, -59.0f / 24.0f, 37.0f / 24.0f, -9.0f / 24.0f);
}

// ---------------------------------------------------------------------------
extern "C" void kernel_launch(void* const* d_in, const int* in_sizes, int n_in,
                              void* d_out, int out_size, void* d_ws, size_t ws_size,
                              hipStream_t stream) {
    const float* x0    = (const float*)d_in[0];
    const float* v0    = (const float*)d_in[1];
    const float* beta  = (const float*)d_in[2];
    const float* ls    = (const float*)d_in[3];
    const float* alpha = (const float*)d_in[4];
    float* out = (float*)d_out;
    _Float16* A = (_Float16*)d_ws;   // 768 halfs: 3 MFMA A-fragments

    int B = in_sizes[0] / 2;         // 50000

    hipLaunchKernelGGL(setup_A_kernel, dim3(12), dim3(64), 0, stream,
                       beta, ls, alpha, A);

    int grid = (B + 15) / 16;        // 3125 single-wave blocks
    hipLaunchKernelGGL(geo_kernel, dim3(grid), dim3(64), 0, stream,
                       x0, v0, A, out, B);
}